// Round 6
// baseline (307.023 us; speedup 1.0000x reference)
//
#include <hip/hip_runtime.h>
#include <math.h>

// Problem constants: B=256, LMAX=512, NCOND=300, NHID=600
#define BB     256
#define LMAX   512
#define NCOND  300
#define NHID   600
#define NSEG   8          // 8 segments of 64 tokens; block = one segment chunk, one col-half
#define CHUNK  64
#define KPAD   320        // K padded to 10 chunks of 32 (k>=300 zero in W1T)
#define KLDS   328        // LDS row stride (elems): 656 B, 16B-aligned
#define NKC    10         // KPAD/32

typedef short s16x8 __attribute__((ext_vector_type(8)));  // MFMA A/B frag (8 bf16)
typedef float f32x4 __attribute__((ext_vector_type(4)));  // MFMA accumulator

// fp32 -> bf16 round-to-nearest-even
__device__ inline unsigned short f2bf(float f) {
    unsigned int x = __float_as_uint(f);
    x += 0x7fffu + ((x >> 16) & 1u);
    return (unsigned short)(x >> 16);
}

// ---------------------------------------------------------------------------
// k0: W1T bf16 FRAGMENT-MAJOR:
//   w1t[((ntile*NKC + kc)*64 + lane)*8 + j] = W1[kc*32+(lane>>4)*8+j][ntile*16+(lane&15)]
// -> a wave's B-frag load is one contiguous 1 KB global_load_dwordx4.
// ---------------------------------------------------------------------------
__global__ __launch_bounds__(256) void k0_w1t(const float* __restrict__ W1,
                                              unsigned short* __restrict__ w1t)
{
    const int t     = blockIdx.x * 256 + threadIdx.x;  // 0..25599
    const int lane  = t & 63;
    const int g     = t >> 6;                          // ntile*NKC + kc
    const int ntile = g / NKC;
    const int kc    = g - ntile * NKC;
    const int n     = ntile * 16 + (lane & 15);
    const int kbase = kc * 32 + (lane >> 4) * 8;
    union { unsigned short us[8]; s16x8 v8; } u;
#pragma unroll
    for (int j = 0; j < 8; ++j) {
        const int k = kbase + j;
        const float w = (n < NHID && k < NCOND) ? W1[(size_t)k * NHID + n] : 0.f;
        u.us[j] = f2bf(w);
    }
    *(s16x8*)(w1t + (size_t)t * 8) = u.v8;
}

// ---------------------------------------------------------------------------
// k1: grid (BB, NSEG, 2), 512 threads = 8 waves.
//     Wave w: n-tiles (w>>1)*5 + {0..4} of its col-half, rows (w&1)*32 + 0..31
//     (2 m-tiles). acc = 5x2 f32x4 = 40 VGPR -> ~120 unified regs/wave ->
//     4 waves/SIMD with __launch_bounds__(512,4) = 16 waves/CU, 2 blocks
//     resident (LDS 2x42 KB) for cross-block stage/compute overlap.
//     Wave pairs (w, w^1) combine row-halves via LDS (atile reused).
// ---------------------------------------------------------------------------
__global__ __launch_bounds__(512, 4) void k1_mfma_pool(
    const float* __restrict__ ctx, const int* __restrict__ lengths,
    const unsigned short* __restrict__ w1t, const float* __restrict__ b1,
    float* __restrict__ partial)
{
    const int b  = blockIdx.x;
    const int s  = blockIdx.y;
    const int ch = blockIdx.z;

    int count = lengths[b]; if (count < 1) count = 1;   // reference clamps lens >= 1
    const int l0 = s * CHUNK;
    if (l0 >= count) return;                            // dead segment
    const int valid = min(count - l0, CHUNK);

    const int tid  = threadIdx.x;
    const int lane = tid & 63;
    const int wv   = tid >> 6;        // 0..7
    const int ln15 = lane & 15;
    const int kg   = lane >> 4;

    __shared__ __align__(16) unsigned short atile[CHUNK * KLDS];   // 41,984 B

    // ---- stage 64 x KPAD bf16 (division-free mapping): thread covers row
    //      r = tid>>3, chunks c8 = (tid&7) + 8p, p = 0..4.
    {
        const int r      = tid >> 3;          // 0..63
        const int c8base = tid & 7;
        const bool inrow = (r < valid);
        const float* rowp = ctx + ((size_t)b * LMAX + l0 + r) * NCOND;
#pragma unroll
        for (int p = 0; p < 5; ++p) {
            const int c8 = c8base + p * 8;    // 0..39
            float4 v0 = make_float4(0.f, 0.f, 0.f, 0.f);
            float4 v1 = make_float4(0.f, 0.f, 0.f, 0.f);
            if (inrow && c8 <= 37) v0 = *(const float4*)(rowp + c8 * 8);
            if (inrow && c8 <= 36) v1 = *(const float4*)(rowp + c8 * 8 + 4);
            union { unsigned short us[8]; s16x8 v8; } u;
            u.us[0] = f2bf(v0.x); u.us[1] = f2bf(v0.y);
            u.us[2] = f2bf(v0.z); u.us[3] = f2bf(v0.w);
            u.us[4] = f2bf(v1.x); u.us[5] = f2bf(v1.y);
            u.us[6] = f2bf(v1.z); u.us[7] = f2bf(v1.w);
            *(s16x8*)(atile + r * KLDS + c8 * 8) = u.v8;
        }
    }
    __syncthreads();

    // ---- MFMA: wave wv -> ntiles (wv>>1)*5+{0..4}, rows (wv&1)*32+{0..31}
    const int ntg   = wv >> 1;                // 0..3 nt-group within col-half
    const int mrow0 = (wv & 1) * 32;          // row-half base
    const int ntile0 = ch * 20 + ntg * 5;
    const unsigned short* bbase = w1t + ((size_t)ntile0 * NKC * 64 + lane) * 8;
    const unsigned short* arow  = atile + (mrow0 + ln15) * KLDS + kg * 8;

    f32x4 acc[5][2];
#pragma unroll
    for (int nt = 0; nt < 5; ++nt)
#pragma unroll
        for (int mt = 0; mt < 2; ++mt) acc[nt][mt] = (f32x4){0.f, 0.f, 0.f, 0.f};

    s16x8 bf[2][5];
#pragma unroll
    for (int nt = 0; nt < 5; ++nt) bf[0][nt] = *(const s16x8*)(bbase + nt * 5120);

#pragma unroll
    for (int kc = 0; kc < NKC; ++kc) {
        const int cur = kc & 1, nxt = cur ^ 1;
        if (kc < NKC - 1) {
#pragma unroll
            for (int nt = 0; nt < 5; ++nt)
                bf[nxt][nt] = *(const s16x8*)(bbase + nt * 5120 + (kc + 1) * 512);
        }
        s16x8 af[2];
#pragma unroll
        for (int mt = 0; mt < 2; ++mt)
            af[mt] = *(const s16x8*)(arow + mt * 16 * KLDS + kc * 32);
#pragma unroll
        for (int nt = 0; nt < 5; ++nt)
#pragma unroll
            for (int mt = 0; mt < 2; ++mt)
                acc[nt][mt] = __builtin_amdgcn_mfma_f32_16x16x32_bf16(
                    af[mt], bf[cur][nt], acc[nt][mt], 0, 0, 0);
    }

    // ---- epilogue: bias + ReLU + row mask, reduce kg via shfl, then combine
    //      wave pairs (row-halves) through LDS (atile reused after barrier).
    __syncthreads();                          // all A-reads done; atile reusable
    float* psums = (float*)atile;             // [8 waves][5 nt][16 cols]

    float wsum[5];
#pragma unroll
    for (int nt = 0; nt < 5; ++nt) {
        const int colg = ch * 320 + ntg * 80 + nt * 16 + ln15;
        const float b1c = (colg < NHID) ? b1[colg] : 0.f;
        float ssum = 0.f;
#pragma unroll
        for (int mt = 0; mt < 2; ++mt) {
            const int rbase = mrow0 + mt * 16 + kg * 4;
#pragma unroll
            for (int r = 0; r < 4; ++r) {
                const float h = fmaxf(acc[nt][mt][r] + b1c, 0.f);
                if (rbase + r < valid) ssum += h;
            }
        }
        ssum += __shfl_xor(ssum, 16, 64);
        ssum += __shfl_xor(ssum, 32, 64);
        wsum[nt] = ssum;
    }
    if (kg == 0) {
#pragma unroll
        for (int nt = 0; nt < 5; ++nt)
            psums[(wv * 5 + nt) * 16 + ln15] = wsum[nt];
    }
    __syncthreads();

    if ((wv & 1) == 0 && kg == 0) {
#pragma unroll
        for (int nt = 0; nt < 5; ++nt) {
            const float tot = psums[(wv * 5 + nt) * 16 + ln15]
                            + psums[((wv + 1) * 5 + nt) * 16 + ln15];
            const int colg = ch * 320 + ntg * 80 + nt * 16 + ln15;
            if (colg < NHID)
                partial[((size_t)s * BB + b) * NHID + colg] = tot;
        }
    }
}

// ---------------------------------------------------------------------------
// k2: 2 batches per block (same-n lanes share Wa loads). Reduce partials over
//     sp < ceil(len/64), /len, gate = sigmoid(pooled@Wa + ba); out = gate*x.
// NHID/4 = 150 float4s = 37*4 + 2 -> 4-wide main loop to h4<148, 2-float4 tail.
// ---------------------------------------------------------------------------
__global__ __launch_bounds__(640) void k2_gate(
    const float* __restrict__ x, const int* __restrict__ lengths,
    const float* __restrict__ partial, const float* __restrict__ Wa,
    const float* __restrict__ ba, float* __restrict__ out)
{
    const int b0  = blockIdx.x * 2;
    const int tid = threadIdx.x;

    __shared__ float pl[2][NHID];

    if (tid < NHID) {
#pragma unroll
        for (int bb = 0; bb < 2; ++bb) {
            int count = lengths[b0 + bb]; if (count < 1) count = 1;
            const int nch = (count + CHUNK - 1) >> 6;
            float ssum = 0.f;
            for (int sp = 0; sp < nch; ++sp)
                ssum += partial[((size_t)sp * BB + (b0 + bb)) * NHID + tid];
            pl[bb][tid] = ssum / (float)count;
        }
    }
    __syncthreads();

    if (tid < 2 * NCOND) {
        const int bb = tid / NCOND;        // 0 or 1
        const int n  = tid - bb * NCOND;   // lanes 0..299 / 300..599 share Wa addrs
        const int b  = b0 + bb;
        float a0 = ba[n], a1 = 0.f, a2 = 0.f, a3 = 0.f;
        const float4* p4 = (const float4*)pl[bb];
        for (int h4 = 0; h4 < 148; h4 += 4) {   // h = 0..591
            const float4 pv0 = p4[h4];
            const float4 pv1 = p4[h4 + 1];
            const float4 pv2 = p4[h4 + 2];
            const float4 pv3 = p4[h4 + 3];
            const int hb = h4 * 4;
            a0 = fmaf(pv0.x, Wa[(size_t)(hb +  0) * NCOND + n], a0);
            a0 = fmaf(pv0.y, Wa[(size_t)(hb +  1) * NCOND + n], a0);
            a0 = fmaf(pv0.z, Wa[(size_t)(hb +  2) * NCOND + n], a0);
            a0 = fmaf(pv0.w, Wa[(size_t)(hb +  3) * NCOND + n], a0);
            a1 = fmaf(pv1.x, Wa[(size_t)(hb +  4) * NCOND + n], a1);
            a1 = fmaf(pv1.y, Wa[(size_t)(hb +  5) * NCOND + n], a1);
            a1 = fmaf(pv1.z, Wa[(size_t)(hb +  6) * NCOND + n], a1);
            a1 = fmaf(pv1.w, Wa[(size_t)(hb +  7) * NCOND + n], a1);
            a2 = fmaf(pv2.x, Wa[(size_t)(hb +  8) * NCOND + n], a2);
            a2 = fmaf(pv2.y, Wa[(size_t)(hb +  9) * NCOND + n], a2);
            a2 = fmaf(pv2.z, Wa[(size_t)(hb + 10) * NCOND + n], a2);
            a2 = fmaf(pv2.w, Wa[(size_t)(hb + 11) * NCOND + n], a2);
            a3 = fmaf(pv3.x, Wa[(size_t)(hb + 12) * NCOND + n], a3);
            a3 = fmaf(pv3.y, Wa[(size_t)(hb + 13) * NCOND + n], a3);
            a3 = fmaf(pv3.z, Wa[(size_t)(hb + 14) * NCOND + n], a3);
            a3 = fmaf(pv3.w, Wa[(size_t)(hb + 15) * NCOND + n], a3);
        }
        {   // tail: h = 592..599
            const float4 pv0 = p4[148];
            const float4 pv1 = p4[149];
            a0 = fmaf(pv0.x, Wa[(size_t)592 * NCOND + n], a0);
            a0 = fmaf(pv0.y, Wa[(size_t)593 * NCOND + n], a0);
            a0 = fmaf(pv0.z, Wa[(size_t)594 * NCOND + n], a0);
            a0 = fmaf(pv0.w, Wa[(size_t)595 * NCOND + n], a0);
            a1 = fmaf(pv1.x, Wa[(size_t)596 * NCOND + n], a1);
            a1 = fmaf(pv1.y, Wa[(size_t)597 * NCOND + n], a1);
            a1 = fmaf(pv1.z, Wa[(size_t)598 * NCOND + n], a1);
            a1 = fmaf(pv1.w, Wa[(size_t)599 * NCOND + n], a1);
        }
        const float acc  = (a0 + a1) + (a2 + a3);
        const float gate = 1.0f / (1.0f + expf(-acc));
        out[(size_t)b * NCOND + n] = gate * x[(size_t)b * NCOND + n];
    }
}

extern "C" void kernel_launch(void* const* d_in, const int* in_sizes, int n_in,
                              void* d_out, int out_size, void* d_ws, size_t ws_size,
                              hipStream_t stream)
{
    // setup_inputs() order: x, context, lengths, W1, b1, Wa, ba
    const float* x       = (const float*)d_in[0];
    const float* ctx     = (const float*)d_in[1];
    const int*   lengths = (const int*)  d_in[2];
    const float* W1      = (const float*)d_in[3];
    const float* b1      = (const float*)d_in[4];
    const float* Wa      = (const float*)d_in[5];
    const float* ba      = (const float*)d_in[6];
    float*       out     = (float*)d_out;

    // ws layout: [w1t frag-major bf16: 409,600 B][partial fp32 8*256*600: 4,915,200 B]
    unsigned short* w1t     = (unsigned short*)d_ws;
    float*          partial = (float*)((char*)d_ws + 409600);

    k0_w1t<<<100, 256, 0, stream>>>(W1, w1t);
    k1_mfma_pool<<<dim3(BB, NSEG, 2), 512, 0, stream>>>(ctx, lengths, w1t, b1, partial);
    k2_gate<<<BB / 2, 640, 0, stream>>>(x, lengths, partial, Wa, ba, out);
}